// Round 3
// baseline (90.729 us; speedup 1.0000x reference)
//
#include <hip/hip_runtime.h>
#include <math.h>

// HypAgg (Poincare ball, c=1), 2 dispatches (r8 = r7 + replay-safe tickets).
//   g_ij = att_ij * atanh(sn_ij)/sn_ij / den_ij
//   support_i = beta_i * ( -S_i x_i + beta_i Y_i ),  S=sum g*alpha, Y=sum g x_j
// hyp_stats: per-row x2 / left / right + bf16 pre-convert/pre-swizzle + ticket zero.
// hyp_main : grid (64 i-tiles x 8 j-chunks), 2 blocks/CU, 2 barriers; stages via
//   global_load_lds width=16 from PRE-SWIZZLED xb/xbT (linear LDS, zero VALU).
//   After partial stores, per-i-tile ticket (agent-scope acq_rel atomic); the
//   8th block re-reads the 8 chunk partials (L3-warm) and does expmap inline,
//   then RESETS its ticket (self-cleaning -> safe under rocprof dispatch replay).
// ws floats: Yp[8*131072] | Sp[8*1024*4] | st_x2[1024] | st_L[1024] | st_R[1024]
//            | xb (131072 bf16) | xbT (131072 bf16) | tickets[64] (uint)

typedef short short8v __attribute__((ext_vector_type(8)));
typedef float float4v __attribute__((ext_vector_type(4)));

static __device__ __forceinline__ short f2bf(float f) {
    unsigned u = __float_as_uint(f);
    u += 0x7fff + ((u >> 16) & 1);   // RNE; inputs never NaN here
    return (short)(u >> 16);
}
static __device__ __forceinline__ float rcpf(float x) { return __builtin_amdgcn_rcpf(x); }
static __device__ __forceinline__ float atanh_over(float pn) {   // atanh(min(pn,1-eps))/pn
    float uu = fminf(pn, 1.f - 1e-7f);
    return 0.5f * __logf((1.f + uu) * rcpf(1.f - uu)) * rcpf(pn);
}
static __device__ __forceinline__ void gload16(const unsigned short* g, unsigned short* l) {
    __builtin_amdgcn_global_load_lds(
        (const __attribute__((address_space(1))) void*)g,
        (__attribute__((address_space(3))) void*)l, 16, 0, 0);
}

// ---------------- kernel 1: per-row stats + bf16 pre-convert/pre-swizzle ----------------
__global__ __launch_bounds__(256) void hyp_stats(
    const float* __restrict__ x, const float* __restrict__ w,
    const float* __restrict__ battp,
    float* __restrict__ st_x2, float* __restrict__ st_L, float* __restrict__ st_R,
    unsigned short* __restrict__ xb, unsigned short* __restrict__ xbT,
    unsigned* __restrict__ tickets)
{
    if (blockIdx.x == 0 && threadIdx.x < 64) tickets[threadIdx.x] = 0u;

    int row  = blockIdx.x * 4 + (threadIdx.x >> 6);
    int lane = threadIdx.x & 63;
    const float* xr = x + row * 128;
    float a0 = xr[lane], a1 = xr[lane + 64];

    // bf16 copies, pre-swizzled: element unit u (8 elems) of row r stored at
    // unit slot u^(r&7). hyp_main stages these linearly and reads with the
    // same XOR -> conflict-free ds_read_b128, zero staging VALU.
    unsigned short b0 = (unsigned short)f2bf(a0);
    unsigned short b1 = (unsigned short)f2bf(a1);
    int r7 = row & 7, l7 = lane & 7;
    xb[row * 128 + ((lane >> 3) ^ r7) * 8 + l7]        = b0;  // units 0..7
    xb[row * 128 + (((lane + 64) >> 3) ^ r7) * 8 + l7] = b1;  // units 8..15 (XOR keeps high bit)
    // xbT layout: [dim d][chunk c][unit u^(d&7)][elem]; here j=row, d=lane(+64)
    int tb = (row >> 7) * 128 + (row & 7);   // chunk base + elem-in-unit
    int uo = (row & 127) >> 3;               // unit within chunk
    xbT[lane * 1024        + tb + (uo ^ l7) * 8] = b0;
    xbT[(lane + 64) * 1024 + tb + (uo ^ l7) * 8] = b1;   // (lane+64)&7 == l7

    float x2 = a0 * a0 + a1 * a1;
    float dl = a0 * w[lane]       + a1 * w[lane + 64];
    float dr = a0 * w[lane + 128] + a1 * w[lane + 192];
    for (int m = 1; m < 64; m <<= 1) {
        x2 += __shfl_xor(x2, m);
        dl += __shfl_xor(dl, m);
        dr += __shfl_xor(dr, m);
    }
    if (lane == 0) {
        float pn = sqrtf(fmaxf(x2, 1e-15f));
        float f  = atanh_over(pn);
        st_x2[row] = x2;
        st_L[row]  = f * dl + battp[0];   // DenseAtt left + bias folded
        st_R[row]  = f * dr;
    }
}

// ---------------- kernel 2: pairwise MFMA + scalar map + last-block expmap ----------------
__global__ __launch_bounds__(256, 2) void hyp_main(
    const float* __restrict__ x, const float* __restrict__ adj,
    const float* __restrict__ st_x2, const float* __restrict__ st_L,
    const float* __restrict__ st_R,
    const unsigned short* __restrict__ xb, const unsigned short* __restrict__ xbT,
    float* __restrict__ Yp, float* __restrict__ Sp,
    unsigned* __restrict__ tickets, float* __restrict__ out)
{
    // linear (swizzled-content) LDS tiles, 16B-aligned slots
    __shared__ __align__(16) unsigned short sXI [16 * 128];   // X_I  (i, dim)
    __shared__ __align__(16) unsigned short sXJ [128 * 128];  // X_J  (j, dim)
    __shared__ __align__(16) unsigned short sXJt[128 * 128];  // X_J^T (dim, j)
    __shared__ __align__(16) unsigned short sW  [16 * 128];   // g weights (i, j)
    __shared__ int sdone;

    const int t    = threadIdx.x;
    const int lane = t & 63;
    const int wave = t >> 6;
    const int n    = lane & 15;
    const int q    = lane >> 4;
    const int i0   = blockIdx.x * 16;
    const int c    = blockIdx.y;
    const int j0   = c * 128;

    // ---- async staging: pre-swizzled global -> linear LDS (17 loads/thread) ----
    gload16(&xb[i0 * 128 + t * 8], &sXI[wave * 512]);
#pragma unroll
    for (int it = 0; it < 8; ++it)
        gload16(&xb[j0 * 128 + (it * 256 + t) * 8], &sXJ[(it * 256 + wave * 64) * 8]);
#pragma unroll
    for (int it = 0; it < 8; ++it) {
        int s = it * 256 + t;                 // slot = d*16 + u
        gload16(&xbT[(s >> 4) * 1024 + j0 + (s & 15) * 8],
                &sXJt[(it * 256 + wave * 64) * 8]);
    }

    // ---- register prefetch (independent; overlaps staging) ----
    float x2i4[4], bi4[4], li4[4];
#pragma unroll
    for (int r = 0; r < 4; ++r) {
        int i = i0 + q * 4 + r;
        x2i4[r] = st_x2[i];
        li4[r]  = st_L[i];
    }
    float x2j2[2], rj2[2], adjv[2][4];
#pragma unroll
    for (int jsl = 0; jsl < 2; ++jsl) {
        int j = j0 + (wave * 2 + jsl) * 16 + n;
        x2j2[jsl] = st_x2[j];
        rj2[jsl]  = st_R[j];
#pragma unroll
        for (int r = 0; r < 4; ++r)
            adjv[jsl][r] = adj[(i0 + q * 4 + r) * 1024 + j];
    }
#pragma unroll
    for (int r = 0; r < 4; ++r) bi4[r] = 1.f - x2i4[r];

    __syncthreads();   // B1: staging visible (compiler drains vmcnt here)

    const int n7 = n & 7;
    // ---- A-frags: row n, unit kk*4+q, swizzled slot ----
    short8v afrag[4];
#pragma unroll
    for (int kk = 0; kk < 4; ++kk)
        afrag[kk] = *(const short8v*)&sXI[(n * 16 + ((kk * 4 + q) ^ n7)) * 8];

    float Sacc[4] = {0.f, 0.f, 0.f, 0.f};

    // ---- phase A: G = X_I * X_J^T + scalar map -> sW, Sacc ----
#pragma unroll
    for (int jsl = 0; jsl < 2; ++jsl) {
        int js = wave * 2 + jsl;
        int jrow = js * 16 + n;               // (jrow&7) == n7
        float4v acc = (float4v){0.f, 0.f, 0.f, 0.f};
#pragma unroll
        for (int kk = 0; kk < 4; ++kk) {
            short8v b = *(const short8v*)&sXJ[(jrow * 16 + ((kk * 4 + q) ^ n7)) * 8];
            acc = __builtin_amdgcn_mfma_f32_16x16x32_bf16(afrag[kk], b, acc, 0, 0, 0);
        }
        float x2j = x2j2[jsl];
        float rj  = rj2[jsl];
#pragma unroll
        for (int r = 0; r < 4; ++r) {
            float G     = acc[r];
            int   i     = q * 4 + r;
            float alpha = 1.f - 2.f * G + x2j;
            float den   = fmaxf(fmaf(x2i4[r], x2j, 1.f - 2.f * G), 1e-15f);
            float rdn   = rcpf(den);
            float bb    = bi4[r];
            float nn2   = alpha * alpha * x2i4[r] + bb * bb * x2j - 2.f * alpha * bb * G;
            float sn    = sqrtf(fmaxf(nn2 * rdn * rdn, 1e-15f));
            float tt    = atanh_over(sn);
            float z     = li4[r] + rj;
            float sig   = rcpf(1.f + __expf(-z));
            float g     = sig * adjv[jsl][r] * tt * rdn;
            Sacc[r]     = fmaf(g, alpha, Sacc[r]);
            // sW element (i, j=js*16+n): unit js*2+(n>>3), slot ^= (i&7)
            sW[(i * 16 + ((js * 2 + (n >> 3)) ^ (i & 7))) * 8 + n7] = (unsigned short)f2bf(g);
        }
    }
    __syncthreads();   // B2: sW ready

    // ---- phase B: Y = W(16x128) * X_J(128x128) via sXJt ----
    float4v accB[2];
    accB[0] = (float4v){0.f, 0.f, 0.f, 0.f};
    accB[1] = (float4v){0.f, 0.f, 0.f, 0.f};
#pragma unroll
    for (int nsl = 0; nsl < 2; ++nsl) {
        int ns = wave * 2 + nsl;
#pragma unroll
        for (int kk = 0; kk < 4; ++kk) {
            short8v a = *(const short8v*)&sW  [(n * 16 + ((kk * 4 + q) ^ n7)) * 8];
            short8v b = *(const short8v*)&sXJt[((ns * 16 + n) * 16 + ((kk * 4 + q) ^ n7)) * 8];
            accB[nsl] = __builtin_amdgcn_mfma_f32_16x16x32_bf16(a, b, accB[nsl], 0, 0, 0);
        }
    }

    // ---- stores: Y partials + wave-reduced S partials ----
    float* Yc = Yp + c * 131072;
#pragma unroll
    for (int nsl = 0; nsl < 2; ++nsl) {
        int ns = wave * 2 + nsl;
#pragma unroll
        for (int r = 0; r < 4; ++r)
            Yc[(i0 + q * 4 + r) * 128 + ns * 16 + n] = accB[nsl][r];
    }
    // reduce Sacc over the 16 n-lanes (stays within q-group), store 4/row/chunk
#pragma unroll
    for (int r = 0; r < 4; ++r) {
#pragma unroll
        for (int m = 1; m < 16; m <<= 1)
            Sacc[r] += __shfl_xor(Sacc[r], m);
    }
    if (n == 0) {
#pragma unroll
        for (int r = 0; r < 4; ++r)
            Sp[(c * 1024 + i0 + q * 4 + r) * 4 + wave] = Sacc[r];
    }

    // ---- last-block finisher: expmap for rows i0..i0+15 ----
    // All stores drained at the barrier (compiler emits vmcnt(0) before
    // s_barrier); the acq_rel agent-scope atomic release-publishes this
    // block's partials so the winner's acquire sees every chunk's stores.
    __syncthreads();
    if (t == 0) {
        unsigned old = __hip_atomic_fetch_add(&tickets[blockIdx.x], 1u,
                          __ATOMIC_ACQ_REL, __HIP_MEMORY_SCOPE_AGENT);
        sdone = (old == 7u);
    }
    __syncthreads();
    if (!sdone) return;
    __builtin_amdgcn_fence(__ATOMIC_ACQUIRE, "agent");   // invalidate stale cache

    const int rl  = t >> 4;          // row-local 0..15
    const int row = i0 + rl;
    const int l16 = t & 15;          // 16 lanes/row, 8 dims/lane
    float4v y0 = (float4v){0.f, 0.f, 0.f, 0.f};
    float4v y1 = (float4v){0.f, 0.f, 0.f, 0.f};
#pragma unroll
    for (int cc = 0; cc < 8; ++cc) {
        const float4v* Yr = (const float4v*)&Yp[cc * 131072 + row * 128];
        y0 += Yr[l16 * 2];
        y1 += Yr[l16 * 2 + 1];
    }
    // 32 S-partials per row: p = chunk*4 + wave; lane reads p=l16 and p=l16+16
    float S = Sp[((l16 >> 2) * 1024 + row) * 4 + (l16 & 3)]
            + Sp[(((l16 + 16) >> 2) * 1024 + row) * 4 + ((l16 + 16) & 3)];
#pragma unroll
    for (int m = 1; m < 16; m <<= 1) S += __shfl_xor(S, m);   // stays in 16-group

    const float4v* x4g = (const float4v*)x;
    float4v xa0 = x4g[row * 32 + l16 * 2];
    float4v xa1 = x4g[row * 32 + l16 * 2 + 1];
    float x2 = st_x2[row];
    float bE = fmaxf(1.f - x2, 1e-15f);
    float u0[4], u1[4], un2p = 0.f, xup = 0.f;
#pragma unroll
    for (int e = 0; e < 4; ++e) {
        u0[e] = bE * (bE * y0[e] - S * xa0[e]);
        u1[e] = bE * (bE * y1[e] - S * xa1[e]);
        un2p += u0[e] * u0[e] + u1[e] * u1[e];
        xup  += xa0[e] * u0[e] + xa1[e] * u1[e];
    }
#pragma unroll
    for (int m = 1; m < 16; m <<= 1) {
        un2p += __shfl_xor(un2p, m);
        xup  += __shfl_xor(xup,  m);
    }
    float un  = sqrtf(fmaxf(un2p, 1e-15f));
    float e2  = __expf(2.f * un * rcpf(bE));
    float th  = 1.f - 2.f * rcpf(e2 + 1.f);   // tanh(un/b)
    float s2  = th * rcpf(un);
    float xy  = s2 * xup;
    float y2s = th * th;
    float coef = 1.f + 2.f * xy + y2s;
    float den  = fmaxf(1.f + 2.f * xy + x2 * y2s, 1e-15f);
    float rd   = rcpf(den);
    float4v o0 = { (coef*xa0[0] + bE*s2*u0[0])*rd, (coef*xa0[1] + bE*s2*u0[1])*rd,
                   (coef*xa0[2] + bE*s2*u0[2])*rd, (coef*xa0[3] + bE*s2*u0[3])*rd };
    float4v o1 = { (coef*xa1[0] + bE*s2*u1[0])*rd, (coef*xa1[1] + bE*s2*u1[1])*rd,
                   (coef*xa1[2] + bE*s2*u1[2])*rd, (coef*xa1[3] + bE*s2*u1[3])*rd };
    ((float4v*)out)[row * 32 + l16 * 2]     = o0;
    ((float4v*)out)[row * 32 + l16 * 2 + 1] = o1;

    // self-clean: ticket back to 0 so a solo replay of this dispatch (rocprof
    // counter groups) still elects exactly one finisher per i-tile.
    if (t == 0)
        __hip_atomic_store(&tickets[blockIdx.x], 0u,
                           __ATOMIC_RELEASE, __HIP_MEMORY_SCOPE_AGENT);
}

extern "C" void kernel_launch(void* const* d_in, const int* in_sizes, int n_in,
                              void* d_out, int out_size, void* d_ws, size_t ws_size,
                              hipStream_t stream) {
    const float* x    = (const float*)d_in[0];
    const float* adj  = (const float*)d_in[1];
    const float* w    = (const float*)d_in[2];
    const float* batt = (const float*)d_in[3];
    float* out = (float*)d_out;

    float* Yp    = (float*)d_ws;             // 8 * 131072 floats (4 MB)
    float* Sp    = Yp + 8 * 131072;          // 8 * 1024 * 4 floats (128 KB)
    float* st_x2 = Sp + 8 * 1024 * 4;        // 1024
    float* st_L  = st_x2 + 1024;             // 1024
    float* st_R  = st_L + 1024;              // 1024
    unsigned short* xb  = (unsigned short*)(st_R + 1024);  // 1024*128 bf16 (256 KB)
    unsigned short* xbT = xb + 1024 * 128;                 // 128*1024 bf16 (256 KB)
    unsigned* tickets   = (unsigned*)(xbT + 1024 * 128);   // 64 uints

    hipLaunchKernelGGL(hyp_stats, dim3(256), dim3(256), 0, stream,
                       x, w, batt, st_x2, st_L, st_R, xb, xbT, tickets);
    hipLaunchKernelGGL(hyp_main, dim3(64, 8), dim3(256), 0, stream,
                       x, adj, st_x2, st_L, st_R, xb, xbT, Yp, Sp, tickets, out);
}

// Round 4
// 72.320 us; speedup vs baseline: 1.2545x; 1.2545x over previous
//
#include <hip/hip_runtime.h>
#include <math.h>

// HypAgg (Poincare ball, c=1), 3 dispatches (r9 = revert to r6, the verified
// best: 73.0us. r7/r8's last-block-finisher fusion regressed to 90.7us —
// agent-scope acq_rel atomics per block force per-block L2 writeback/invalidate
// on non-coherent XCDs, far costlier than one kernel-boundary drain).
//   g_ij = att_ij * atanh(sn_ij)/sn_ij / den_ij
//   support_i = beta_i * ( -S_i x_i + beta_i Y_i ),  S=sum g*alpha, Y=sum g x_j
// hyp_stats: per-row x2 / left / right + bf16 pre-convert/pre-swizzle.
// hyp_main : grid (64 i-tiles x 8 j-chunks), 2 blocks/CU, 2 barriers; stages via
//   global_load_lds width=16 from PRE-SWIZZLED xb/xbT (linear LDS, zero VALU).
// hyp_exp  : sums 8 Y partials + 32 S partials per row + expmap (128 blocks).
// ws floats: Yp[8*131072] | Sp[8*1024*4] | st_x2[1024] | st_L[1024] | st_R[1024]
//            | xb (131072 bf16) | xbT (131072 bf16)

typedef short short8v __attribute__((ext_vector_type(8)));
typedef float float4v __attribute__((ext_vector_type(4)));

static __device__ __forceinline__ short f2bf(float f) {
    unsigned u = __float_as_uint(f);
    u += 0x7fff + ((u >> 16) & 1);   // RNE; inputs never NaN here
    return (short)(u >> 16);
}
static __device__ __forceinline__ float rcpf(float x) { return __builtin_amdgcn_rcpf(x); }
static __device__ __forceinline__ float atanh_over(float pn) {   // atanh(min(pn,1-eps))/pn
    float uu = fminf(pn, 1.f - 1e-7f);
    return 0.5f * __logf((1.f + uu) * rcpf(1.f - uu)) * rcpf(pn);
}
static __device__ __forceinline__ void gload16(const unsigned short* g, unsigned short* l) {
    __builtin_amdgcn_global_load_lds(
        (const __attribute__((address_space(1))) void*)g,
        (__attribute__((address_space(3))) void*)l, 16, 0, 0);
}

// ---------------- kernel 1: per-row stats + bf16 pre-convert/pre-swizzle ----------------
__global__ __launch_bounds__(256) void hyp_stats(
    const float* __restrict__ x, const float* __restrict__ w,
    const float* __restrict__ battp,
    float* __restrict__ st_x2, float* __restrict__ st_L, float* __restrict__ st_R,
    unsigned short* __restrict__ xb, unsigned short* __restrict__ xbT)
{
    int row  = blockIdx.x * 4 + (threadIdx.x >> 6);
    int lane = threadIdx.x & 63;
    const float* xr = x + row * 128;
    float a0 = xr[lane], a1 = xr[lane + 64];

    // bf16 copies, pre-swizzled: element unit u (8 elems) of row r stored at
    // unit slot u^(r&7). hyp_main stages these linearly and reads with the
    // same XOR -> conflict-free ds_read_b128, zero staging VALU.
    unsigned short b0 = (unsigned short)f2bf(a0);
    unsigned short b1 = (unsigned short)f2bf(a1);
    int r7 = row & 7, l7 = lane & 7;
    xb[row * 128 + ((lane >> 3) ^ r7) * 8 + l7]        = b0;  // units 0..7
    xb[row * 128 + (((lane + 64) >> 3) ^ r7) * 8 + l7] = b1;  // units 8..15 (XOR keeps high bit)
    // xbT layout: [dim d][chunk c][unit u^(d&7)][elem]; here j=row, d=lane(+64)
    int tb = (row >> 7) * 128 + (row & 7);   // chunk base + elem-in-unit
    int uo = (row & 127) >> 3;               // unit within chunk
    xbT[lane * 1024        + tb + (uo ^ l7) * 8] = b0;
    xbT[(lane + 64) * 1024 + tb + (uo ^ l7) * 8] = b1;   // (lane+64)&7 == l7

    float x2 = a0 * a0 + a1 * a1;
    float dl = a0 * w[lane]       + a1 * w[lane + 64];
    float dr = a0 * w[lane + 128] + a1 * w[lane + 192];
    for (int m = 1; m < 64; m <<= 1) {
        x2 += __shfl_xor(x2, m);
        dl += __shfl_xor(dl, m);
        dr += __shfl_xor(dr, m);
    }
    if (lane == 0) {
        float pn = sqrtf(fmaxf(x2, 1e-15f));
        float f  = atanh_over(pn);
        st_x2[row] = x2;
        st_L[row]  = f * dl + battp[0];   // DenseAtt left + bias folded
        st_R[row]  = f * dr;
    }
}

// ---------------- kernel 2: pairwise MFMA + scalar map (2 barriers) ----------------
__global__ __launch_bounds__(256, 2) void hyp_main(
    const float* __restrict__ adj,
    const float* __restrict__ st_x2, const float* __restrict__ st_L,
    const float* __restrict__ st_R,
    const unsigned short* __restrict__ xb, const unsigned short* __restrict__ xbT,
    float* __restrict__ Yp, float* __restrict__ Sp)
{
    // linear (swizzled-content) LDS tiles, 16B-aligned slots
    __shared__ __align__(16) unsigned short sXI [16 * 128];   // X_I  (i, dim)
    __shared__ __align__(16) unsigned short sXJ [128 * 128];  // X_J  (j, dim)
    __shared__ __align__(16) unsigned short sXJt[128 * 128];  // X_J^T (dim, j)
    __shared__ __align__(16) unsigned short sW  [16 * 128];   // g weights (i, j)

    const int t    = threadIdx.x;
    const int lane = t & 63;
    const int wave = t >> 6;
    const int n    = lane & 15;
    const int q    = lane >> 4;
    const int i0   = blockIdx.x * 16;
    const int c    = blockIdx.y;
    const int j0   = c * 128;

    // ---- async staging: pre-swizzled global -> linear LDS (17 loads/thread) ----
    gload16(&xb[i0 * 128 + t * 8], &sXI[wave * 512]);
#pragma unroll
    for (int it = 0; it < 8; ++it)
        gload16(&xb[j0 * 128 + (it * 256 + t) * 8], &sXJ[(it * 256 + wave * 64) * 8]);
#pragma unroll
    for (int it = 0; it < 8; ++it) {
        int s = it * 256 + t;                 // slot = d*16 + u
        gload16(&xbT[(s >> 4) * 1024 + j0 + (s & 15) * 8],
                &sXJt[(it * 256 + wave * 64) * 8]);
    }

    // ---- register prefetch (independent; overlaps staging) ----
    float x2i4[4], bi4[4], li4[4];
#pragma unroll
    for (int r = 0; r < 4; ++r) {
        int i = i0 + q * 4 + r;
        x2i4[r] = st_x2[i];
        li4[r]  = st_L[i];
    }
    float x2j2[2], rj2[2], adjv[2][4];
#pragma unroll
    for (int jsl = 0; jsl < 2; ++jsl) {
        int j = j0 + (wave * 2 + jsl) * 16 + n;
        x2j2[jsl] = st_x2[j];
        rj2[jsl]  = st_R[j];
#pragma unroll
        for (int r = 0; r < 4; ++r)
            adjv[jsl][r] = adj[(i0 + q * 4 + r) * 1024 + j];
    }
#pragma unroll
    for (int r = 0; r < 4; ++r) bi4[r] = 1.f - x2i4[r];

    __syncthreads();   // B1: staging visible (compiler drains vmcnt here)

    const int n7 = n & 7;
    // ---- A-frags: row n, unit kk*4+q, swizzled slot ----
    short8v afrag[4];
#pragma unroll
    for (int kk = 0; kk < 4; ++kk)
        afrag[kk] = *(const short8v*)&sXI[(n * 16 + ((kk * 4 + q) ^ n7)) * 8];

    float Sacc[4] = {0.f, 0.f, 0.f, 0.f};

    // ---- phase A: G = X_I * X_J^T + scalar map -> sW, Sacc ----
#pragma unroll
    for (int jsl = 0; jsl < 2; ++jsl) {
        int js = wave * 2 + jsl;
        int jrow = js * 16 + n;               // (jrow&7) == n7
        float4v acc = (float4v){0.f, 0.f, 0.f, 0.f};
#pragma unroll
        for (int kk = 0; kk < 4; ++kk) {
            short8v b = *(const short8v*)&sXJ[(jrow * 16 + ((kk * 4 + q) ^ n7)) * 8];
            acc = __builtin_amdgcn_mfma_f32_16x16x32_bf16(afrag[kk], b, acc, 0, 0, 0);
        }
        float x2j = x2j2[jsl];
        float rj  = rj2[jsl];
#pragma unroll
        for (int r = 0; r < 4; ++r) {
            float G     = acc[r];
            int   i     = q * 4 + r;
            float alpha = 1.f - 2.f * G + x2j;
            float den   = fmaxf(fmaf(x2i4[r], x2j, 1.f - 2.f * G), 1e-15f);
            float rdn   = rcpf(den);
            float bb    = bi4[r];
            float nn2   = alpha * alpha * x2i4[r] + bb * bb * x2j - 2.f * alpha * bb * G;
            float sn    = sqrtf(fmaxf(nn2 * rdn * rdn, 1e-15f));
            float tt    = atanh_over(sn);
            float z     = li4[r] + rj;
            float sig   = rcpf(1.f + __expf(-z));
            float g     = sig * adjv[jsl][r] * tt * rdn;
            Sacc[r]     = fmaf(g, alpha, Sacc[r]);
            // sW element (i, j=js*16+n): unit js*2+(n>>3), slot ^= (i&7)
            sW[(i * 16 + ((js * 2 + (n >> 3)) ^ (i & 7))) * 8 + n7] = (unsigned short)f2bf(g);
        }
    }
    __syncthreads();   // B2: sW ready

    // ---- phase B: Y = W(16x128) * X_J(128x128) via sXJt ----
    float4v accB[2];
    accB[0] = (float4v){0.f, 0.f, 0.f, 0.f};
    accB[1] = (float4v){0.f, 0.f, 0.f, 0.f};
#pragma unroll
    for (int nsl = 0; nsl < 2; ++nsl) {
        int ns = wave * 2 + nsl;
#pragma unroll
        for (int kk = 0; kk < 4; ++kk) {
            short8v a = *(const short8v*)&sW  [(n * 16 + ((kk * 4 + q) ^ n7)) * 8];
            short8v b = *(const short8v*)&sXJt[((ns * 16 + n) * 16 + ((kk * 4 + q) ^ n7)) * 8];
            accB[nsl] = __builtin_amdgcn_mfma_f32_16x16x32_bf16(a, b, accB[nsl], 0, 0, 0);
        }
    }

    // ---- stores: Y partials + wave-reduced S partials ----
    float* Yc = Yp + c * 131072;
#pragma unroll
    for (int nsl = 0; nsl < 2; ++nsl) {
        int ns = wave * 2 + nsl;
#pragma unroll
        for (int r = 0; r < 4; ++r)
            Yc[(i0 + q * 4 + r) * 128 + ns * 16 + n] = accB[nsl][r];
    }
    // reduce Sacc over the 16 n-lanes (stays within q-group), store 4/row/chunk
#pragma unroll
    for (int r = 0; r < 4; ++r) {
#pragma unroll
        for (int m = 1; m < 16; m <<= 1)
            Sacc[r] += __shfl_xor(Sacc[r], m);
    }
    if (n == 0) {
#pragma unroll
        for (int r = 0; r < 4; ++r)
            Sp[(c * 1024 + i0 + q * 4 + r) * 4 + wave] = Sacc[r];
    }
}

// ---------------- kernel 3: sum partials + expmap ----------------
// 128 blocks x 256 threads: 8 rows/block, 32 lanes/row, 4 dims/lane.
__global__ __launch_bounds__(256) void hyp_exp(
    const float* __restrict__ x, const float* __restrict__ Yp,
    const float* __restrict__ Sp, const float* __restrict__ st_x2,
    float* __restrict__ out)
{
    const int t   = threadIdx.x;
    const int row = blockIdx.x * 8 + (t >> 5);
    const int l32 = t & 31;
    float4v y = (float4v){0.f, 0.f, 0.f, 0.f};
#pragma unroll
    for (int c = 0; c < 8; ++c)
        y += *(const float4v*)&Yp[c * 131072 + row * 128 + l32 * 4];
    // 32 S-partials per row: lane l32 -> chunk l32>>2, wave l32&3
    float S = Sp[((l32 >> 2) * 1024 + row) * 4 + (l32 & 3)];
#pragma unroll
    for (int m = 1; m < 32; m <<= 1) S += __shfl_xor(S, m, 32);

    float4v xa = ((const float4v*)x)[row * 32 + l32];
    float x2 = st_x2[row];
    float bE = fmaxf(1.f - x2, 1e-15f);
    float u[4], un2p = 0.f, xup = 0.f;
#pragma unroll
    for (int e = 0; e < 4; ++e) {
        u[e] = bE * (bE * y[e] - S * xa[e]);
        un2p += u[e] * u[e];
        xup  += xa[e] * u[e];
    }
#pragma unroll
    for (int m = 1; m < 32; m <<= 1) {
        un2p += __shfl_xor(un2p, m, 32);
        xup  += __shfl_xor(xup,  m, 32);
    }
    float un  = sqrtf(fmaxf(un2p, 1e-15f));
    float e2  = __expf(2.f * un * rcpf(bE));
    float th  = 1.f - 2.f * rcpf(e2 + 1.f);   // tanh(un/b)
    float s2  = th * rcpf(un);
    float xy  = s2 * xup;
    float y2s = th * th;
    float coef = 1.f + 2.f * xy + y2s;
    float den  = fmaxf(1.f + 2.f * xy + x2 * y2s, 1e-15f);
    float rd   = rcpf(den);
    float4v o = { (coef*xa[0] + bE*s2*u[0])*rd, (coef*xa[1] + bE*s2*u[1])*rd,
                  (coef*xa[2] + bE*s2*u[2])*rd, (coef*xa[3] + bE*s2*u[3])*rd };
    ((float4v*)out)[row * 32 + l32] = o;
}

extern "C" void kernel_launch(void* const* d_in, const int* in_sizes, int n_in,
                              void* d_out, int out_size, void* d_ws, size_t ws_size,
                              hipStream_t stream) {
    const float* x    = (const float*)d_in[0];
    const float* adj  = (const float*)d_in[1];
    const float* w    = (const float*)d_in[2];
    const float* batt = (const float*)d_in[3];
    float* out = (float*)d_out;

    float* Yp    = (float*)d_ws;             // 8 * 131072 floats (4 MB)
    float* Sp    = Yp + 8 * 131072;          // 8 * 1024 * 4 floats (128 KB)
    float* st_x2 = Sp + 8 * 1024 * 4;        // 1024
    float* st_L  = st_x2 + 1024;             // 1024
    float* st_R  = st_L + 1024;              // 1024
    unsigned short* xb  = (unsigned short*)(st_R + 1024);  // 1024*128 bf16 (256 KB)
    unsigned short* xbT = xb + 1024 * 128;                 // 128*1024 bf16 (256 KB)

    hipLaunchKernelGGL(hyp_stats, dim3(256), dim3(256), 0, stream,
                       x, w, batt, st_x2, st_L, st_R, xb, xbT);
    hipLaunchKernelGGL(hyp_main, dim3(64, 8), dim3(256), 0, stream,
                       adj, st_x2, st_L, st_R, xb, xbT, Yp, Sp);
    hipLaunchKernelGGL(hyp_exp, dim3(128), dim3(256), 0, stream,
                       x, Yp, Sp, st_x2, out);
}